// Round 16
// baseline (839.475 us; speedup 1.0000x reference)
//
#include <hip/hip_runtime.h>

// Problem constants (fixed by reference)
#define NN 20000          // nodes
#define NEDGE 320000      // edges
#define D 256             // hidden dim
#define RD 512            // router/expert input dim (2*D)
#define OD 128            // output dim
#define NEXP 8            // experts
#define NSLOT (2*NN)      // top-2 assignment slots
#define NODE_BLOCKS 79    // ceil(NN/256)
#define ASSIGN_BLOCKS 157 // ceil(2*NN/256)
#define EXP_BLOCKS 640    // max 64-row expert tiles (40960/64)

typedef unsigned short u16;
typedef __attribute__((ext_vector_type(4))) short short4v;
typedef __attribute__((ext_vector_type(8))) short short8v;
typedef __attribute__((ext_vector_type(16))) float f32x16;

// exact 3-way bf16 split: v == H + M + L (bit-truncation; 24 mantissa bits)
__device__ __forceinline__ void split1(float v, u16& h, u16& m, u16& l) {
    unsigned b = __float_as_uint(v);
    h = (u16)(b >> 16);
    float fh = __uint_as_float(b & 0xffff0000u);
    float r1 = v - fh;
    unsigned b1 = __float_as_uint(r1);
    m = (u16)(b1 >> 16);
    float fm = __uint_as_float(b1 & 0xffff0000u);
    float r2 = r1 - fm;
    l = (u16)(__float_as_uint(r2) >> 16);
}

// ---------------------------------------------------------------------------
// small helper kernels
// ---------------------------------------------------------------------------

__global__ void copy_x_zero_cnt_k(const float* __restrict__ x, float* __restrict__ r,
                                  int* __restrict__ cnt) {
    int gid = blockIdx.x * 256 + threadIdx.x;
    int n = gid >> 6;
    int c4 = gid & 63;
    if (gid < NN * (D / 4)) {
        float4 v = reinterpret_cast<const float4*>(x)[gid];
        reinterpret_cast<float4*>(r + (size_t)n * RD)[c4] = v;
    }
    if (gid < NN) cnt[gid] = 0;
}

__global__ void count_edges_k(const int* __restrict__ dst, int* __restrict__ cnt) {
    int e = blockIdx.x * 256 + threadIdx.x;
    if (e < NEDGE) atomicAdd(&cnt[dst[e]], 1);
}

__global__ void block_sums_k(const int* __restrict__ cnt, int* __restrict__ bsum) {
    __shared__ int s[256];
    int i = blockIdx.x * 256 + threadIdx.x;
    s[threadIdx.x] = (i < NN) ? cnt[i] : 0;
    __syncthreads();
    for (int off = 128; off > 0; off >>= 1) {
        if (threadIdx.x < off) s[threadIdx.x] += s[threadIdx.x + off];
        __syncthreads();
    }
    if (threadIdx.x == 0) bsum[blockIdx.x] = s[0];
}

__global__ void scan_bsums_k(int* __restrict__ bsum, int* __restrict__ row_start) {
    if (blockIdx.x == 0 && threadIdx.x == 0) {
        int acc = 0;
        for (int i = 0; i < NODE_BLOCKS; i++) { int t = bsum[i]; bsum[i] = acc; acc += t; }
        row_start[NN] = acc;
    }
}

__global__ void block_scan_k(const int* __restrict__ cnt, const int* __restrict__ bsum,
                             int* __restrict__ row_start, int* __restrict__ cur) {
    __shared__ int s[256];
    int i = blockIdx.x * 256 + threadIdx.x;
    int v = (i < NN) ? cnt[i] : 0;
    s[threadIdx.x] = v;
    __syncthreads();
    for (int off = 1; off < 256; off <<= 1) {
        int t = (threadIdx.x >= off) ? s[threadIdx.x - off] : 0;
        __syncthreads();
        s[threadIdx.x] += t;
        __syncthreads();
    }
    int excl = s[threadIdx.x] - v + bsum[blockIdx.x];
    if (i < NN) { row_start[i] = excl; cur[i] = excl; }
}

__global__ void fill_csr_k(const int* __restrict__ src, const int* __restrict__ dst,
                           int* __restrict__ cur, int* __restrict__ csr_src) {
    int e = blockIdx.x * 256 + threadIdx.x;
    if (e < NEDGE) {
        int pos = atomicAdd(&cur[dst[e]], 1);
        csr_src[pos] = src[e];
    }
}

// FUSED aggregate + router: one wave per node. Compute agg (mean over
// incoming neighbors) in registers, store to r[:,256:512], then compute the
// hierarchical-router outputs using in-register agg + one float4 load of h.
__global__ void agg_router_k(float* __restrict__ r, const int* __restrict__ row_start,
                             const int* __restrict__ csr_src,
                             const float* __restrict__ Wg, const float* __restrict__ We,
                             const float* __restrict__ wc,
                             int* __restrict__ node_top, float* __restrict__ node_gate,
                             float* __restrict__ conf) {
    int wid = blockIdx.x * 4 + (threadIdx.x >> 6);
    int lane = threadIdx.x & 63;
    if (wid >= NN) return;

    // ---- aggregate (identical numerics to round 13) ----
    int beg = row_start[wid], end = row_start[wid + 1];
    float ax = 0.f, ay = 0.f, az = 0.f, aw = 0.f;
    for (int j = beg; j < end; j++) {
        int s = csr_src[j];
        float4 v = reinterpret_cast<const float4*>(r + (size_t)s * RD)[lane];
        ax += v.x; ay += v.y; az += v.z; aw += v.w;
    }
    float deg = (float)((end - beg) > 1 ? (end - beg) : 1);
    float4 av = make_float4(ax / deg, ay / deg, az / deg, aw / deg);
    reinterpret_cast<float4*>(r + (size_t)wid * RD + D)[lane] = av;

    // ---- router: lane owns dims 4*lane..4*lane+3 (h) and D+4*lane.. (agg) ----
    float4 hv = reinterpret_cast<const float4*>(r + (size_t)wid * RD)[lane];
    float pg[4] = {0, 0, 0, 0};
    float pe[8] = {0, 0, 0, 0, 0, 0, 0, 0};
    float pc = 0.f;
    auto step = [&](int k, float rv) {
        float4 wg = *reinterpret_cast<const float4*>(Wg + (size_t)k * 4);
        pg[0] = fmaf(rv, wg.x, pg[0]); pg[1] = fmaf(rv, wg.y, pg[1]);
        pg[2] = fmaf(rv, wg.z, pg[2]); pg[3] = fmaf(rv, wg.w, pg[3]);
        float4 w0 = *reinterpret_cast<const float4*>(We + (size_t)k * 8);
        float4 w1 = *reinterpret_cast<const float4*>(We + (size_t)k * 8 + 4);
        pe[0] = fmaf(rv, w0.x, pe[0]); pe[1] = fmaf(rv, w0.y, pe[1]);
        pe[2] = fmaf(rv, w0.z, pe[2]); pe[3] = fmaf(rv, w0.w, pe[3]);
        pe[4] = fmaf(rv, w1.x, pe[4]); pe[5] = fmaf(rv, w1.y, pe[5]);
        pe[6] = fmaf(rv, w1.z, pe[6]); pe[7] = fmaf(rv, w1.w, pe[7]);
        pc = fmaf(rv, wc[k], pc);
    };
    int k0 = 4 * lane;
    step(k0 + 0, hv.x); step(k0 + 1, hv.y); step(k0 + 2, hv.z); step(k0 + 3, hv.w);
    int k1 = D + 4 * lane;
    step(k1 + 0, av.x); step(k1 + 1, av.y); step(k1 + 2, av.z); step(k1 + 3, av.w);

#pragma unroll
    for (int off = 32; off > 0; off >>= 1) {
#pragma unroll
        for (int g = 0; g < 4; g++) pg[g] += __shfl_xor(pg[g], off);
#pragma unroll
        for (int g = 0; g < 8; g++) pe[g] += __shfl_xor(pe[g], off);
        pc += __shfl_xor(pc, off);
    }

    if (lane == 0) {
        float m = fmaxf(fmaxf(pg[0], pg[1]), fmaxf(pg[2], pg[3]));
        float eg[4]; float sg = 0.f;
#pragma unroll
        for (int g = 0; g < 4; g++) { eg[g] = expf(pg[g] - m); sg += eg[g]; }
        float probs[8];
#pragma unroll
        for (int g = 0; g < 4; g++) {
            float a = pe[2 * g], b = pe[2 * g + 1];
            float mm = fmaxf(a, b);
            float ea = expf(a - mm), eb = expf(b - mm);
            float inv = 1.f / (ea + eb);
            float gp = eg[g] / sg;
            probs[2 * g]     = gp * ea * inv;
            probs[2 * g + 1] = gp * eb * inv;
        }
        int i0 = 0; float v0 = probs[0];
#pragma unroll
        for (int j = 1; j < 8; j++) if (probs[j] > v0) { v0 = probs[j]; i0 = j; }
        int i1 = -1; float v1 = -1e30f;
#pragma unroll
        for (int j = 0; j < 8; j++) if (j != i0 && probs[j] > v1) { v1 = probs[j]; i1 = j; }
        float s = v0 + v1 + 1e-9f;
        node_top[2 * wid] = i0;  node_top[2 * wid + 1] = i1;
        node_gate[2 * wid] = v0 / s;  node_gate[2 * wid + 1] = v1 / s;
        conf[wid] = 1.f / (1.f + expf(-pc));
    }
}

// per-block partial histogram (no global atomics)
__global__ void hist_part_k(const int* __restrict__ node_top, int* __restrict__ part) {
    __shared__ int h[NEXP];
    if (threadIdx.x < NEXP) h[threadIdx.x] = 0;
    __syncthreads();
    int i = blockIdx.x * 256 + threadIdx.x;
    if (i < NSLOT) atomicAdd(&h[node_top[i]], 1);
    __syncthreads();
    if (threadIdx.x < NEXP) part[blockIdx.x * NEXP + threadIdx.x] = h[threadIdx.x];
}

__global__ void scan2_k(const int* __restrict__ part, int* __restrict__ es,
                        int* __restrict__ ecur) {
    __shared__ int tot[NEXP];
    if (threadIdx.x < NEXP) {
        int s = 0;
        for (int b = 0; b < ASSIGN_BLOCKS; b++) s += part[b * NEXP + threadIdx.x];
        tot[threadIdx.x] = s;
        ecur[threadIdx.x] = 0;
    }
    __syncthreads();
    if (threadIdx.x == 0) {
        int acc = 0;
        for (int e = 0; e < NEXP; e++) { es[e] = acc; acc += tot[e]; }
        es[NEXP] = acc;
    }
}

__global__ void fill_experts_k(const int* __restrict__ node_top, const float* __restrict__ node_gate,
                               const int* __restrict__ es, int* __restrict__ ecur,
                               int* __restrict__ slot_node, float* __restrict__ slot_gate,
                               int* __restrict__ node_slot) {
    __shared__ int hcnt[NEXP], hbase[NEXP];
    int tid = threadIdx.x;
    if (tid < NEXP) hcnt[tid] = 0;
    __syncthreads();
    int i = blockIdx.x * 256 + tid;
    int e = 0, local = 0;
    bool act = (i < NSLOT);
    if (act) {
        e = node_top[i];
        local = atomicAdd(&hcnt[e], 1);
    }
    __syncthreads();
    if (tid < NEXP) hbase[tid] = (hcnt[tid] > 0) ? atomicAdd(&ecur[tid], hcnt[tid]) : 0;
    __syncthreads();
    if (act) {
        int slot = es[e] + hbase[e] + local;
        slot_node[slot] = i >> 1;
        slot_gate[slot] = node_gate[i];
        node_slot[i] = slot;
    }
}

// h_next = relu(conf*(expout[s0]+expout[s1]) + (1-conf)*weak), into r[:, :256]
__global__ void combine_k(const float* __restrict__ expout, const float* __restrict__ weak,
                          const float* __restrict__ conf, const int* __restrict__ node_slot,
                          float* __restrict__ r) {
    int gid = blockIdx.x * 256 + threadIdx.x;
    if (gid >= NN * (D / 4)) return;
    int n = gid >> 6, c4 = gid & 63;
    int s0 = node_slot[2 * n], s1 = node_slot[2 * n + 1];
    float4 e0 = reinterpret_cast<const float4*>(expout + (size_t)s0 * D)[c4];
    float4 e1 = reinterpret_cast<const float4*>(expout + (size_t)s1 * D)[c4];
    float4 w  = reinterpret_cast<const float4*>(weak + (size_t)n * D)[c4];
    float cf = conf[n], cg = 1.f - cf;
    float4 o;
    o.x = fmaxf(cf * (e0.x + e1.x) + cg * w.x, 0.f);
    o.y = fmaxf(cf * (e0.y + e1.y) + cg * w.y, 0.f);
    o.z = fmaxf(cf * (e0.z + e1.z) + cg * w.z, 0.f);
    o.w = fmaxf(cf * (e0.w + e1.w) + cg * w.w, 0.f);
    reinterpret_cast<float4*>(r + (size_t)n * RD)[c4] = o;
}

// ---------------------------------------------------------------------------
// weight -> fragment-ready tiled bf16x3 planes.
// src: nm matrices [K][N] f32. dst planes: [nm][N/32][K/16][64][8] u16 where
// tile (mat,nb,kb), lane l, elem j holds B[kb*16 + (l>>5)*8 + j][nb*32 + (l&31)].
// ---------------------------------------------------------------------------
__device__ __forceinline__ void btile_one(const float* __restrict__ src,
                                          u16* __restrict__ dH, u16* __restrict__ dM,
                                          u16* __restrict__ dL, int K, int N, int gid) {
    int l = gid & 63;
    int tile = gid >> 6;
    int K16 = K >> 4;
    int kb = tile % K16;
    int t2 = tile / K16;
    int N32 = N >> 5;
    int nb = t2 % N32;
    int mat = t2 / N32;
    int kbase = (kb << 4) + ((l >> 5) << 3);
    int n = (nb << 5) + (l & 31);
    const float* s = src + ((size_t)mat * K + kbase) * N + n;
    short8v vh, vm, vl;
#pragma unroll
    for (int j = 0; j < 8; j++) {
        u16 hh, mm, ll;
        split1(s[(size_t)j * N], hh, mm, ll);
        vh[j] = (short)hh; vm[j] = (short)mm; vl[j] = (short)ll;
    }
    size_t o = (size_t)gid * 8;
    *reinterpret_cast<short8v*>(dH + o) = vh;
    *reinterpret_cast<short8v*>(dM + o) = vm;
    *reinterpret_cast<short8v*>(dL + o) = vl;
}

__global__ void btile_k(const float* __restrict__ src, u16* __restrict__ dH,
                        u16* __restrict__ dM, u16* __restrict__ dL,
                        int K, int N, int total) {
    int gid = blockIdx.x * 256 + threadIdx.x;
    if (gid >= total) return;
    btile_one(src, dH, dM, dL, K, N, gid);
}

// fused per-layer weight prep: W1 (131072 units) + W2 (65536) + Ww (16384)
__global__ void btile3_k(const float* __restrict__ s1, u16* __restrict__ aH,
                         u16* __restrict__ aM, u16* __restrict__ aL,
                         const float* __restrict__ s2, u16* __restrict__ bH,
                         u16* __restrict__ bM, u16* __restrict__ bL,
                         const float* __restrict__ s3, u16* __restrict__ cH,
                         u16* __restrict__ cM, u16* __restrict__ cL) {
    int gid = blockIdx.x * 256 + threadIdx.x;
    if (gid < 131072) {
        btile_one(s1, aH, aM, aL, RD, D, gid);
    } else if (gid < 131072 + 65536) {
        btile_one(s2, bH, bM, bL, D, D, gid - 131072);
    } else if (gid < 131072 + 65536 + 16384) {
        btile_one(s3, cH, cM, cL, RD, D, gid - 131072 - 65536);
    }
}

// ALL-layer weight prep in one launch: 3x(W1+W2+Ww) + Wout. 643072 units.
__global__ void btile_all_k(const float* __restrict__ W1, u16* __restrict__ aH,
                            u16* __restrict__ aM, u16* __restrict__ aL,
                            const float* __restrict__ W2, u16* __restrict__ bH,
                            u16* __restrict__ bM, u16* __restrict__ bL,
                            const float* __restrict__ Ww, u16* __restrict__ cH,
                            u16* __restrict__ cM, u16* __restrict__ cL,
                            const float* __restrict__ Wout, u16* __restrict__ oH,
                            u16* __restrict__ oM, u16* __restrict__ oL) {
    int gid = blockIdx.x * 256 + threadIdx.x;
    const int L1 = 131072, L2 = 65536, L3 = 16384, PER = L1 + L2 + L3;
    if (gid < 3 * PER) {
        int l = gid / PER, g = gid - l * PER;
        if (g < L1) {
            btile_one(W1 + (size_t)l * NEXP * RD * D, aH + (size_t)l * L1 * 8,
                      aM + (size_t)l * L1 * 8, aL + (size_t)l * L1 * 8, RD, D, g);
        } else if (g < L1 + L2) {
            btile_one(W2 + (size_t)l * NEXP * D * D, bH + (size_t)l * L2 * 8,
                      bM + (size_t)l * L2 * 8, bL + (size_t)l * L2 * 8, D, D, g - L1);
        } else {
            btile_one(Ww + (size_t)l * RD * D, cH + (size_t)l * L3 * 8,
                      cM + (size_t)l * L3 * 8, cL + (size_t)l * L3 * 8, RD, D,
                      g - L1 - L2);
        }
    } else if (gid < 3 * PER + 4096) {
        btile_one(Wout, oH, oM, oL, D, OD, gid - 3 * PER);
    }
}

// ---------------------------------------------------------------------------
// bf16x3 split MFMA GEMM, 64x128 block tile (round-8 config: measured best).
// 4 waves of 32x64 (1x2 frags of 32x32x16). A: f32 split on the fly into
// frag-ready LDS (6 KB, single buffer). B: fragment-tiled bf16 planes,
// global->reg (coalesced 1KB/wave, L2/L3-resident).
// MODE 0: plain rows -> C.
// MODE 1: FUSED launch: bx < weak_base -> expert rows via slot_node,
//         +bias, relu -> hid[slot]; bx >= weak_base -> weak GEMM
//         (direct rows of A, B=V planes, plain store -> Cw).
// MODE 2: rows are slots; (acc+bias)*gate -> C[slot] (slot-indexed store).
// ---------------------------------------------------------------------------
template <int MODE>
__global__ __launch_bounds__(256, 5) void gemm_mfma(
    const float* __restrict__ A, int lda,
    const u16* __restrict__ BH, const u16* __restrict__ BM,
    const u16* __restrict__ BL,
    const float* __restrict__ bias,
    float* __restrict__ C, int ldc,
    const int* __restrict__ es,
    const int* __restrict__ slot_node,
    const float* __restrict__ slot_gate,
    int M, int N, int K,
    const u16* __restrict__ VH, const u16* __restrict__ VM,
    const u16* __restrict__ VL, float* __restrict__ Cw,
    int weak_base, int Mw) {
    constexpr int PL2 = 1024;   // one plane: [rowgrp2][kh2][row32][j8] u16
    __shared__ u16 sA[3 * PL2]; // 6,144 B

    int tid = threadIdx.x;
    int row0, valid_rows;
    bool isweak = false;
    if (MODE == 0) {
        row0 = blockIdx.x * 64;
        valid_rows = M - row0; if (valid_rows > 64) valid_rows = 64;
    } else if (MODE == 1 && (int)blockIdx.x >= weak_base) {
        isweak = true;
        row0 = ((int)blockIdx.x - weak_base) * 64;
        valid_rows = Mw - row0; if (valid_rows > 64) valid_rows = 64;
        if (valid_rows <= 0) return;
        BH = VH; BM = VM; BL = VL;
        C = Cw;
    } else {
        int bx = blockIdx.x, acc0 = 0, expert = -1, mt = 0;
        row0 = 0; valid_rows = 0;
        for (int e = 0; e < NEXP; e++) {
            int c = es[e + 1] - es[e];
            int t = (c + 63) >> 6;
            if (bx < acc0 + t) {
                expert = e; mt = bx - acc0; row0 = es[e] + (mt << 6);
                valid_rows = c - (mt << 6); if (valid_rows > 64) valid_rows = 64;
                break;
            }
            acc0 += t;
        }
        if (expert < 0) return;
        int bo = expert * N * K;   // max 8*256*512 = 1M elems, fits int
        BH += bo; BM += bo; BL += bo;
        bias += expert * D;
    }
    int ncol0 = blockIdx.y * 128;

    // A staging: 4 threads per row, each one float4 (4 k)
    int srow = tid >> 2;
    int koff = (tid & 3) * 4;
    int grow;
    {
        int i0 = row0 + srow;
        if (MODE == 1 && !isweak) {
            i0 = i0 < NSLOT ? i0 : NSLOT - 1;
            grow = slot_node[i0];
        } else if (MODE == 2) {
            grow = i0 < M ? i0 : M - 1;
        } else if (MODE == 1) {   // weak
            grow = i0 < Mw ? i0 : Mw - 1;
        } else {
            grow = i0 < M ? i0 : M - 1;
        }
    }
    const float* pA = A + (size_t)grow * lda + koff;
    // frag-ready write offset: [rowgrp][kh][row32][j8]
    int woff = ((srow >> 5) * 2 + (koff >> 3)) * 256 + (srow & 31) * 8 + (koff & 4);

    // fragment coords: wave owns 32 rows x 64 cols (1x2 frags)
    int lane = tid & 63;
    int wave = tid >> 6;
    int wr = (wave & 1) * 32;
    int wc = (wave >> 1) * 64;
    int fl = lane & 31;
    int K16 = K >> 4;
    int nb0 = (ncol0 + wc) >> 5;
    int tbase0 = nb0 * K16 * 512 + lane * 8;
    int tbase1 = (nb0 + 1) * K16 * 512 + lane * 8;
    int roff = ((wr >> 5) * 2 + (lane >> 5)) * 256 + fl * 8;

    f32x16 acc0 = {};
    f32x16 acc1 = {};

    for (int kt = 0; kt < K; kt += 16) {
        float4 av = *reinterpret_cast<const float4*>(pA + kt);
        int ko = (kt >> 4) * 512;
        short8v bH0 = *reinterpret_cast<const short8v*>(BH + tbase0 + ko);
        short8v bM0 = *reinterpret_cast<const short8v*>(BM + tbase0 + ko);
        short8v bL0 = *reinterpret_cast<const short8v*>(BL + tbase0 + ko);
        short8v bH1 = *reinterpret_cast<const short8v*>(BH + tbase1 + ko);
        short8v bM1 = *reinterpret_cast<const short8v*>(BM + tbase1 + ko);
        short8v bL1 = *reinterpret_cast<const short8v*>(BL + tbase1 + ko);
        __syncthreads();
        {
            u16 h0, m0, l0, h1, m1, l1, h2, m2, l2, h3, m3, l3;
            split1(av.x, h0, m0, l0);
            split1(av.y, h1, m1, l1);
            split1(av.z, h2, m2, l2);
            split1(av.w, h3, m3, l3);
            short4v hv = {(short)h0, (short)h1, (short)h2, (short)h3};
            short4v mv = {(short)m0, (short)m1, (short)m2, (short)m3};
            short4v lv = {(short)l0, (short)l1, (short)l2, (short)l3};
            *reinterpret_cast<short4v*>(&sA[0 * PL2 + woff]) = hv;
            *reinterpret_cast<short4v*>(&sA[1 * PL2 + woff]) = mv;
            *reinterpret_cast<short4v*>(&sA[2 * PL2 + woff]) = lv;
        }
        __syncthreads();
        short8v aH = *reinterpret_cast<const short8v*>(&sA[0 * PL2 + roff]);
        short8v aM = *reinterpret_cast<const short8v*>(&sA[1 * PL2 + roff]);
        short8v aL = *reinterpret_cast<const short8v*>(&sA[2 * PL2 + roff]);
#define MFMA_ACC(d, a, b) d = __builtin_amdgcn_mfma_f32_32x32x16_bf16(a, b, d, 0, 0, 0)
        MFMA_ACC(acc0, aH, bH0); MFMA_ACC(acc0, aH, bM0);
        MFMA_ACC(acc0, aM, bH0); MFMA_ACC(acc0, aH, bL0);
        MFMA_ACC(acc0, aM, bM0); MFMA_ACC(acc0, aL, bH0);
        MFMA_ACC(acc1, aH, bH1); MFMA_ACC(acc1, aH, bM1);
        MFMA_ACC(acc1, aM, bH1); MFMA_ACC(acc1, aH, bL1);
        MFMA_ACC(acc1, aM, bM1); MFMA_ACC(acc1, aL, bH1);
#undef MFMA_ACC
    }

    // epilogue: C/D layout col=lane&31, row=(reg&3)+8*(reg>>2)+4*(lane>>5)
    int fh = lane >> 5;
#pragma unroll
    for (int j = 0; j < 2; j++) {
        const f32x16& a = j ? acc1 : acc0;
        int colg = ncol0 + wc + j * 32 + fl;
        float bv = (MODE != 0 && !isweak) ? bias[colg] : 0.f;
#pragma unroll
        for (int rg = 0; rg < 16; rg++) {
            int lrow = wr + (rg & 3) + 8 * (rg >> 2) + 4 * fh;
            if (lrow >= valid_rows) continue;
            int growo = row0 + lrow;
            float v = a[rg] + bv;
            if (MODE == 1 && !isweak) {
                v = fmaxf(v, 0.f);
            } else if (MODE == 2) {
                v *= slot_gate[growo];
            }
            C[(size_t)growo * ldc + colg] = v;
        }
    }
}

// ---------------------------------------------------------------------------
extern "C" void kernel_launch(void* const* d_in, const int* in_sizes, int n_in,
                              void* d_out, int out_size, void* d_ws, size_t ws_size,
                              hipStream_t stream) {
    (void)in_sizes; (void)n_in; (void)out_size;
    const float* x    = (const float*)d_in[0];
    const int*   ei   = (const int*)d_in[1];
    const float* Wg   = (const float*)d_in[2];
    const float* We   = (const float*)d_in[3];
    const float* Ww   = (const float*)d_in[4];
    const float* W1   = (const float*)d_in[5];
    const float* b1   = (const float*)d_in[6];
    const float* W2   = (const float*)d_in[7];
    const float* b2   = (const float*)d_in[8];
    const float* wcp  = (const float*)d_in[9];
    const float* Wout = (const float*)d_in[10];
    float* out = (float*)d_out;

    char* p = (char*)d_ws;
    auto alloc = [&](size_t bytes) -> char* {
        char* q = p; p += (bytes + 255) & ~(size_t)255; return q;
    };
    int*   cnt       = (int*)alloc((size_t)NN * 4);
    int*   row_start = (int*)alloc((size_t)(NN + 1) * 4);
    int*   cur       = (int*)alloc((size_t)NN * 4);
    int*   bsum      = (int*)alloc(128 * 4);
    int*   csr_src   = (int*)alloc((size_t)NEDGE * 4);
    float* r         = (float*)alloc((size_t)NN * RD * 4);
    float* hid       = (float*)alloc((size_t)NSLOT * D * 4);
    float* expout    = (float*)alloc((size_t)NSLOT * D * 4);
    float* weak      = (float*)alloc((size_t)NN * D * 4);
    float* conf      = (float*)alloc((size_t)NN * 4);
    int*   node_top  = (int*)alloc((size_t)2 * NN * 4);
    float* node_gate = (float*)alloc((size_t)2 * NN * 4);
    int*   node_slot = (int*)alloc((size_t)2 * NN * 4);
    int*   slot_node = (int*)alloc((size_t)NSLOT * 4);
    float* slot_gate = (float*)alloc((size_t)NSLOT * 4);
    int*   part      = (int*)alloc((size_t)ASSIGN_BLOCKS * NEXP * 4);
    int*   es        = (int*)alloc(64 * 4);
    int*   ecur      = (int*)alloc(64 * 4);

    // plane sizes (elems) per layer
    const size_t SZ1 = (size_t)NEXP * D * RD;   // 1,048,576
    const size_t SZ2 = (size_t)NEXP * D * D;    //   524,288
    const size_t SZW = (size_t)RD * D;          //   131,072
    const size_t SZO = (size_t)OD * D;          //    65,536
    // decide: all-3-layer plane precompute if workspace allows
    size_t used = (size_t)(p - (char*)d_ws);
    size_t need3 = 3 * 3 * (SZ1 + SZ2 + SZW) * 2 + 3 * SZO * 2 + 16384;
    bool all3 = used + need3 <= ws_size;
    int nl = all3 ? 3 : 1;
    u16* w1tH = (u16*)alloc((size_t)nl * SZ1 * 2);
    u16* w1tM = (u16*)alloc((size_t)nl * SZ1 * 2);
    u16* w1tL = (u16*)alloc((size_t)nl * SZ1 * 2);
    u16* w2tH = (u16*)alloc((size_t)nl * SZ2 * 2);
    u16* w2tM = (u16*)alloc((size_t)nl * SZ2 * 2);
    u16* w2tL = (u16*)alloc((size_t)nl * SZ2 * 2);
    u16* wwtH = (u16*)alloc((size_t)nl * SZW * 2);
    u16* wwtM = (u16*)alloc((size_t)nl * SZW * 2);
    u16* wwtL = (u16*)alloc((size_t)nl * SZW * 2);
    u16* wotH = (u16*)alloc(SZO * 2);
    u16* wotM = (u16*)alloc(SZO * 2);
    u16* wotL = (u16*)alloc(SZO * 2);

    const int* srcp = ei;
    const int* dstp = ei + NEDGE;
    const int EB = (NEDGE + 255) / 256;

    // graph prep (once per launch)
    copy_x_zero_cnt_k<<<5000, 256, 0, stream>>>(x, r, cnt);
    count_edges_k<<<EB, 256, 0, stream>>>(dstp, cnt);
    block_sums_k<<<NODE_BLOCKS, 256, 0, stream>>>(cnt, bsum);
    scan_bsums_k<<<1, 64, 0, stream>>>(bsum, row_start);
    block_scan_k<<<NODE_BLOCKS, 256, 0, stream>>>(cnt, bsum, row_start, cur);
    fill_csr_k<<<EB, 256, 0, stream>>>(srcp, dstp, cur, csr_src);
    if (all3) {
        // all weight planes (3 layers + Wout) in one launch
        btile_all_k<<<2512, 256, 0, stream>>>(W1, w1tH, w1tM, w1tL,
                                              W2, w2tH, w2tM, w2tL,
                                              Ww, wwtH, wwtM, wwtL,
                                              Wout, wotH, wotM, wotL);
    } else {
        btile_k<<<16, 256, 0, stream>>>(Wout, wotH, wotM, wotL, D, OD, 4096);
    }

    for (int l = 0; l < 3; l++) {
        if (!all3) {
            btile3_k<<<832, 256, 0, stream>>>(
                W1 + (size_t)l * NEXP * RD * D, w1tH, w1tM, w1tL,
                W2 + (size_t)l * NEXP * D * D,  w2tH, w2tM, w2tL,
                Ww + (size_t)l * RD * D,        wwtH, wwtM, wwtL);
        }
        size_t o1 = all3 ? (size_t)l * SZ1 : 0;
        size_t o2 = all3 ? (size_t)l * SZ2 : 0;
        size_t ow = all3 ? (size_t)l * SZW : 0;

        agg_router_k<<<5000, 256, 0, stream>>>(r, row_start, csr_src,
            Wg + (size_t)l * RD * 4, We + (size_t)l * RD * 8, wcp + (size_t)l * RD,
            node_top, node_gate, conf);
        hist_part_k<<<ASSIGN_BLOCKS, 256, 0, stream>>>(node_top, part);
        scan2_k<<<1, 64, 0, stream>>>(part, es, ecur);
        fill_experts_k<<<ASSIGN_BLOCKS, 256, 0, stream>>>(node_top, node_gate, es, ecur,
                                                          slot_node, slot_gate, node_slot);
        // FUSED: hid[slot] = relu(r[node]@W1[e]+b1[e])  ||  weak = r@Ww
        gemm_mfma<1><<<dim3(EXP_BLOCKS + 313, 2), 256, 0, stream>>>(
            r, RD, w1tH + o1, w1tM + o1, w1tL + o1, b1 + (size_t)l * NEXP * D, hid, D,
            es, slot_node, slot_gate, NSLOT, D, RD,
            wwtH + ow, wwtM + ow, wwtL + ow, weak, EXP_BLOCKS, NN);
        // expout[slot] = (hid[slot]@W2[e]+b2[e])*gate[slot]  (slot-indexed store)
        gemm_mfma<2><<<dim3(EXP_BLOCKS, 2), 256, 0, stream>>>(
            hid, D, w2tH + o2, w2tM + o2, w2tL + o2, b2 + (size_t)l * NEXP * D, expout, D,
            es, slot_node, slot_gate, NSLOT, D, D,
            nullptr, nullptr, nullptr, nullptr, 1 << 30, 0);
        combine_k<<<5000, 256, 0, stream>>>(expout, weak, conf, node_slot, r);
    }
    // out = h @ Wout  (h = r[:, :256], so K=256 over lda=512)
    gemm_mfma<0><<<dim3(313, 1), 256, 0, stream>>>(
        r, RD, wotH, wotM, wotL, nullptr, out, OD,
        nullptr, nullptr, nullptr, NN, OD, D,
        nullptr, nullptr, nullptr, nullptr, 1 << 30, 0);
}

// Round 17
// 775.982 us; speedup vs baseline: 1.0818x; 1.0818x over previous
//
#include <hip/hip_runtime.h>

// Problem constants (fixed by reference)
#define NN 20000          // nodes
#define NEDGE 320000      // edges
#define D 256             // hidden dim
#define RD 512            // router/expert input dim (2*D)
#define OD 128            // output dim
#define NEXP 8            // experts
#define NSLOT (2*NN)      // top-2 assignment slots
#define NODE_BLOCKS 79    // ceil(NN/256)
#define ASSIGN_BLOCKS 157 // ceil(2*NN/256)
#define EXP_BLOCKS 640    // max 64-row expert tiles (40960/64)

typedef unsigned short u16;
typedef __attribute__((ext_vector_type(4))) short short4v;
typedef __attribute__((ext_vector_type(8))) short short8v;
typedef __attribute__((ext_vector_type(16))) float f32x16;

// exact 3-way bf16 split: v == H + M + L (bit-truncation; 24 mantissa bits)
__device__ __forceinline__ void split1(float v, u16& h, u16& m, u16& l) {
    unsigned b = __float_as_uint(v);
    h = (u16)(b >> 16);
    float fh = __uint_as_float(b & 0xffff0000u);
    float r1 = v - fh;
    unsigned b1 = __float_as_uint(r1);
    m = (u16)(b1 >> 16);
    float fm = __uint_as_float(b1 & 0xffff0000u);
    float r2 = r1 - fm;
    l = (u16)(__float_as_uint(r2) >> 16);
}

// ---------------------------------------------------------------------------
// small helper kernels
// ---------------------------------------------------------------------------

__global__ void copy_x_zero_cnt_k(const float* __restrict__ x, float* __restrict__ r,
                                  int* __restrict__ cnt) {
    int gid = blockIdx.x * 256 + threadIdx.x;
    int n = gid >> 6;
    int c4 = gid & 63;
    if (gid < NN * (D / 4)) {
        float4 v = reinterpret_cast<const float4*>(x)[gid];
        reinterpret_cast<float4*>(r + (size_t)n * RD)[c4] = v;
    }
    if (gid < NN) cnt[gid] = 0;
}

__global__ void count_edges_k(const int* __restrict__ dst, int* __restrict__ cnt) {
    int e = blockIdx.x * 256 + threadIdx.x;
    if (e < NEDGE) atomicAdd(&cnt[dst[e]], 1);
}

__global__ void block_sums_k(const int* __restrict__ cnt, int* __restrict__ bsum) {
    __shared__ int s[256];
    int i = blockIdx.x * 256 + threadIdx.x;
    s[threadIdx.x] = (i < NN) ? cnt[i] : 0;
    __syncthreads();
    for (int off = 128; off > 0; off >>= 1) {
        if (threadIdx.x < off) s[threadIdx.x] += s[threadIdx.x + off];
        __syncthreads();
    }
    if (threadIdx.x == 0) bsum[blockIdx.x] = s[0];
}

__global__ void scan_bsums_k(int* __restrict__ bsum, int* __restrict__ row_start) {
    if (blockIdx.x == 0 && threadIdx.x == 0) {
        int acc = 0;
        for (int i = 0; i < NODE_BLOCKS; i++) { int t = bsum[i]; bsum[i] = acc; acc += t; }
        row_start[NN] = acc;
    }
}

__global__ void block_scan_k(const int* __restrict__ cnt, const int* __restrict__ bsum,
                             int* __restrict__ row_start, int* __restrict__ cur) {
    __shared__ int s[256];
    int i = blockIdx.x * 256 + threadIdx.x;
    int v = (i < NN) ? cnt[i] : 0;
    s[threadIdx.x] = v;
    __syncthreads();
    for (int off = 1; off < 256; off <<= 1) {
        int t = (threadIdx.x >= off) ? s[threadIdx.x - off] : 0;
        __syncthreads();
        s[threadIdx.x] += t;
        __syncthreads();
    }
    int excl = s[threadIdx.x] - v + bsum[blockIdx.x];
    if (i < NN) { row_start[i] = excl; cur[i] = excl; }
}

__global__ void fill_csr_k(const int* __restrict__ src, const int* __restrict__ dst,
                           int* __restrict__ cur, int* __restrict__ csr_src) {
    int e = blockIdx.x * 256 + threadIdx.x;
    if (e < NEDGE) {
        int pos = atomicAdd(&cur[dst[e]], 1);
        csr_src[pos] = src[e];
    }
}

// FUSED aggregate + router with PERMUTED router weights (coalesced loads).
// Permutation: P[hf*256 + j*64 + lane] = W[hf*256 + 4*lane + j]; the math and
// per-lane accumulation order are identical to the (passing) unpermuted fused
// version -- only weight addresses change (16B lane-stride, fully coalesced).
__global__ void agg_router_k(float* __restrict__ r, const int* __restrict__ row_start,
                             const int* __restrict__ csr_src,
                             const float4* __restrict__ WgP,
                             const float4* __restrict__ WeLo,
                             const float4* __restrict__ WeHi,
                             const float* __restrict__ wcP,
                             int* __restrict__ node_top, float* __restrict__ node_gate,
                             float* __restrict__ conf) {
    int wid = blockIdx.x * 4 + (threadIdx.x >> 6);
    int lane = threadIdx.x & 63;
    if (wid >= NN) return;

    // ---- aggregate (identical numerics to round 13) ----
    int beg = row_start[wid], end = row_start[wid + 1];
    float ax = 0.f, ay = 0.f, az = 0.f, aw = 0.f;
    for (int j = beg; j < end; j++) {
        int s = csr_src[j];
        float4 v = reinterpret_cast<const float4*>(r + (size_t)s * RD)[lane];
        ax += v.x; ay += v.y; az += v.z; aw += v.w;
    }
    float deg = (float)((end - beg) > 1 ? (end - beg) : 1);
    float4 av = make_float4(ax / deg, ay / deg, az / deg, aw / deg);
    reinterpret_cast<float4*>(r + (size_t)wid * RD + D)[lane] = av;

    // ---- router: lane owns dims 4*lane..4*lane+3 (h) and D+4*lane.. (agg) ----
    float4 hv = reinterpret_cast<const float4*>(r + (size_t)wid * RD)[lane];
    float pg[4] = {0, 0, 0, 0};
    float pe[8] = {0, 0, 0, 0, 0, 0, 0, 0};
    float pc = 0.f;
    auto step = [&](int rp, float rv) {
        float4 wg = WgP[rp];
        pg[0] = fmaf(rv, wg.x, pg[0]); pg[1] = fmaf(rv, wg.y, pg[1]);
        pg[2] = fmaf(rv, wg.z, pg[2]); pg[3] = fmaf(rv, wg.w, pg[3]);
        float4 w0 = WeLo[rp];
        float4 w1 = WeHi[rp];
        pe[0] = fmaf(rv, w0.x, pe[0]); pe[1] = fmaf(rv, w0.y, pe[1]);
        pe[2] = fmaf(rv, w0.z, pe[2]); pe[3] = fmaf(rv, w0.w, pe[3]);
        pe[4] = fmaf(rv, w1.x, pe[4]); pe[5] = fmaf(rv, w1.y, pe[5]);
        pe[6] = fmaf(rv, w1.z, pe[6]); pe[7] = fmaf(rv, w1.w, pe[7]);
        pc = fmaf(rv, wcP[rp], pc);
    };
    // h half: source k = 4*lane + j  -> permuted row rp = j*64 + lane
    step(lane +   0, hv.x); step(lane +  64, hv.y);
    step(lane + 128, hv.z); step(lane + 192, hv.w);
    // agg half: source k = 256 + 4*lane + j -> rp = 256 + j*64 + lane
    step(256 + lane +   0, av.x); step(256 + lane +  64, av.y);
    step(256 + lane + 128, av.z); step(256 + lane + 192, av.w);

#pragma unroll
    for (int off = 32; off > 0; off >>= 1) {
#pragma unroll
        for (int g = 0; g < 4; g++) pg[g] += __shfl_xor(pg[g], off);
#pragma unroll
        for (int g = 0; g < 8; g++) pe[g] += __shfl_xor(pe[g], off);
        pc += __shfl_xor(pc, off);
    }

    if (lane == 0) {
        float m = fmaxf(fmaxf(pg[0], pg[1]), fmaxf(pg[2], pg[3]));
        float eg[4]; float sg = 0.f;
#pragma unroll
        for (int g = 0; g < 4; g++) { eg[g] = expf(pg[g] - m); sg += eg[g]; }
        float probs[8];
#pragma unroll
        for (int g = 0; g < 4; g++) {
            float a = pe[2 * g], b = pe[2 * g + 1];
            float mm = fmaxf(a, b);
            float ea = expf(a - mm), eb = expf(b - mm);
            float inv = 1.f / (ea + eb);
            float gp = eg[g] / sg;
            probs[2 * g]     = gp * ea * inv;
            probs[2 * g + 1] = gp * eb * inv;
        }
        int i0 = 0; float v0 = probs[0];
#pragma unroll
        for (int j = 1; j < 8; j++) if (probs[j] > v0) { v0 = probs[j]; i0 = j; }
        int i1 = -1; float v1 = -1e30f;
#pragma unroll
        for (int j = 0; j < 8; j++) if (j != i0 && probs[j] > v1) { v1 = probs[j]; i1 = j; }
        float s = v0 + v1 + 1e-9f;
        node_top[2 * wid] = i0;  node_top[2 * wid + 1] = i1;
        node_gate[2 * wid] = v0 / s;  node_gate[2 * wid + 1] = v1 / s;
        conf[wid] = 1.f / (1.f + expf(-pc));
    }
}

// per-block partial histogram (no global atomics)
__global__ void hist_part_k(const int* __restrict__ node_top, int* __restrict__ part) {
    __shared__ int h[NEXP];
    if (threadIdx.x < NEXP) h[threadIdx.x] = 0;
    __syncthreads();
    int i = blockIdx.x * 256 + threadIdx.x;
    if (i < NSLOT) atomicAdd(&h[node_top[i]], 1);
    __syncthreads();
    if (threadIdx.x < NEXP) part[blockIdx.x * NEXP + threadIdx.x] = h[threadIdx.x];
}

__global__ void scan2_k(const int* __restrict__ part, int* __restrict__ es,
                        int* __restrict__ ecur) {
    __shared__ int tot[NEXP];
    if (threadIdx.x < NEXP) {
        int s = 0;
        for (int b = 0; b < ASSIGN_BLOCKS; b++) s += part[b * NEXP + threadIdx.x];
        tot[threadIdx.x] = s;
        ecur[threadIdx.x] = 0;
    }
    __syncthreads();
    if (threadIdx.x == 0) {
        int acc = 0;
        for (int e = 0; e < NEXP; e++) { es[e] = acc; acc += tot[e]; }
        es[NEXP] = acc;
    }
}

__global__ void fill_experts_k(const int* __restrict__ node_top, const float* __restrict__ node_gate,
                               const int* __restrict__ es, int* __restrict__ ecur,
                               int* __restrict__ slot_node, float* __restrict__ slot_gate,
                               int* __restrict__ node_slot) {
    __shared__ int hcnt[NEXP], hbase[NEXP];
    int tid = threadIdx.x;
    if (tid < NEXP) hcnt[tid] = 0;
    __syncthreads();
    int i = blockIdx.x * 256 + tid;
    int e = 0, local = 0;
    bool act = (i < NSLOT);
    if (act) {
        e = node_top[i];
        local = atomicAdd(&hcnt[e], 1);
    }
    __syncthreads();
    if (tid < NEXP) hbase[tid] = (hcnt[tid] > 0) ? atomicAdd(&ecur[tid], hcnt[tid]) : 0;
    __syncthreads();
    if (act) {
        int slot = es[e] + hbase[e] + local;
        slot_node[slot] = i >> 1;
        slot_gate[slot] = node_gate[i];
        node_slot[i] = slot;
    }
}

// h_next = relu(conf*(expout[s0]+expout[s1]) + (1-conf)*weak), into r[:, :256]
__global__ void combine_k(const float* __restrict__ expout, const float* __restrict__ weak,
                          const float* __restrict__ conf, const int* __restrict__ node_slot,
                          float* __restrict__ r) {
    int gid = blockIdx.x * 256 + threadIdx.x;
    if (gid >= NN * (D / 4)) return;
    int n = gid >> 6, c4 = gid & 63;
    int s0 = node_slot[2 * n], s1 = node_slot[2 * n + 1];
    float4 e0 = reinterpret_cast<const float4*>(expout + (size_t)s0 * D)[c4];
    float4 e1 = reinterpret_cast<const float4*>(expout + (size_t)s1 * D)[c4];
    float4 w  = reinterpret_cast<const float4*>(weak + (size_t)n * D)[c4];
    float cf = conf[n], cg = 1.f - cf;
    float4 o;
    o.x = fmaxf(cf * (e0.x + e1.x) + cg * w.x, 0.f);
    o.y = fmaxf(cf * (e0.y + e1.y) + cg * w.y, 0.f);
    o.z = fmaxf(cf * (e0.z + e1.z) + cg * w.z, 0.f);
    o.w = fmaxf(cf * (e0.w + e1.w) + cg * w.w, 0.f);
    reinterpret_cast<float4*>(r + (size_t)n * RD)[c4] = o;
}

// ---------------------------------------------------------------------------
// weight -> fragment-ready tiled bf16x3 planes.
// ---------------------------------------------------------------------------
__device__ __forceinline__ void btile_one(const float* __restrict__ src,
                                          u16* __restrict__ dH, u16* __restrict__ dM,
                                          u16* __restrict__ dL, int K, int N, int gid) {
    int l = gid & 63;
    int tile = gid >> 6;
    int K16 = K >> 4;
    int kb = tile % K16;
    int t2 = tile / K16;
    int N32 = N >> 5;
    int nb = t2 % N32;
    int mat = t2 / N32;
    int kbase = (kb << 4) + ((l >> 5) << 3);
    int n = (nb << 5) + (l & 31);
    const float* s = src + ((size_t)mat * K + kbase) * N + n;
    short8v vh, vm, vl;
#pragma unroll
    for (int j = 0; j < 8; j++) {
        u16 hh, mm, ll;
        split1(s[(size_t)j * N], hh, mm, ll);
        vh[j] = (short)hh; vm[j] = (short)mm; vl[j] = (short)ll;
    }
    size_t o = (size_t)gid * 8;
    *reinterpret_cast<short8v*>(dH + o) = vh;
    *reinterpret_cast<short8v*>(dM + o) = vm;
    *reinterpret_cast<short8v*>(dL + o) = vl;
}

// router-weight permutation: one item = one (layer, k) row
__device__ __forceinline__ void rwperm_one(const float* __restrict__ Wg,
                                           const float* __restrict__ We,
                                           const float* __restrict__ wc,
                                           float4* __restrict__ WgP,
                                           float4* __restrict__ WeLo,
                                           float4* __restrict__ WeHi,
                                           float* __restrict__ wcP, int idx) {
    int l = idx >> 9;           // /512
    int k = idx & 511;
    int kk = k & 255, hf = k >> 8;
    int lane = kk >> 2, j = kk & 3;
    int rp = (l << 9) + hf * 256 + j * 64 + lane;
    const float* wgr = Wg + ((size_t)l * RD + k) * 4;
    WgP[rp] = make_float4(wgr[0], wgr[1], wgr[2], wgr[3]);
    const float* wer = We + ((size_t)l * RD + k) * 8;
    WeLo[rp] = make_float4(wer[0], wer[1], wer[2], wer[3]);
    WeHi[rp] = make_float4(wer[4], wer[5], wer[6], wer[7]);
    wcP[rp] = wc[(size_t)l * RD + k];
}

__global__ void btile_k(const float* __restrict__ src, u16* __restrict__ dH,
                        u16* __restrict__ dM, u16* __restrict__ dL,
                        int K, int N, int total) {
    int gid = blockIdx.x * 256 + threadIdx.x;
    if (gid >= total) return;
    btile_one(src, dH, dM, dL, K, N, gid);
}

// fused per-layer weight prep (fallback path)
__global__ void btile3_k(const float* __restrict__ s1, u16* __restrict__ aH,
                         u16* __restrict__ aM, u16* __restrict__ aL,
                         const float* __restrict__ s2, u16* __restrict__ bH,
                         u16* __restrict__ bM, u16* __restrict__ bL,
                         const float* __restrict__ s3, u16* __restrict__ cH,
                         u16* __restrict__ cM, u16* __restrict__ cL) {
    int gid = blockIdx.x * 256 + threadIdx.x;
    if (gid < 131072) {
        btile_one(s1, aH, aM, aL, RD, D, gid);
    } else if (gid < 131072 + 65536) {
        btile_one(s2, bH, bM, bL, D, D, gid - 131072);
    } else if (gid < 131072 + 65536 + 16384) {
        btile_one(s3, cH, cM, cL, RD, D, gid - 131072 - 65536);
    }
}

__global__ void rw_perm_k(const float* __restrict__ Wg, const float* __restrict__ We,
                          const float* __restrict__ wc, float4* __restrict__ WgP,
                          float4* __restrict__ WeLo, float4* __restrict__ WeHi,
                          float* __restrict__ wcP) {
    int gid = blockIdx.x * 256 + threadIdx.x;
    if (gid < 3 * RD) rwperm_one(Wg, We, wc, WgP, WeLo, WeHi, wcP, gid);
}

// ALL-layer weight prep in one launch: 3x(W1+W2+Ww) + Wout + router perm
__global__ void btile_all_k(const float* __restrict__ W1, u16* __restrict__ aH,
                            u16* __restrict__ aM, u16* __restrict__ aL,
                            const float* __restrict__ W2, u16* __restrict__ bH,
                            u16* __restrict__ bM, u16* __restrict__ bL,
                            const float* __restrict__ Ww, u16* __restrict__ cH,
                            u16* __restrict__ cM, u16* __restrict__ cL,
                            const float* __restrict__ Wout, u16* __restrict__ oH,
                            u16* __restrict__ oM, u16* __restrict__ oL,
                            const float* __restrict__ Wg, const float* __restrict__ We,
                            const float* __restrict__ wc, float4* __restrict__ WgP,
                            float4* __restrict__ WeLo, float4* __restrict__ WeHi,
                            float* __restrict__ wcP) {
    int gid = blockIdx.x * 256 + threadIdx.x;
    const int L1 = 131072, L2 = 65536, L3 = 16384, PER = L1 + L2 + L3;
    if (gid < 3 * PER) {
        int l = gid / PER, g = gid - l * PER;
        if (g < L1) {
            btile_one(W1 + (size_t)l * NEXP * RD * D, aH + (size_t)l * L1 * 8,
                      aM + (size_t)l * L1 * 8, aL + (size_t)l * L1 * 8, RD, D, g);
        } else if (g < L1 + L2) {
            btile_one(W2 + (size_t)l * NEXP * D * D, bH + (size_t)l * L2 * 8,
                      bM + (size_t)l * L2 * 8, bL + (size_t)l * L2 * 8, D, D, g - L1);
        } else {
            btile_one(Ww + (size_t)l * RD * D, cH + (size_t)l * L3 * 8,
                      cM + (size_t)l * L3 * 8, cL + (size_t)l * L3 * 8, RD, D,
                      g - L1 - L2);
        }
    } else if (gid < 3 * PER + 4096) {
        btile_one(Wout, oH, oM, oL, D, OD, gid - 3 * PER);
    } else if (gid < 3 * PER + 4096 + 3 * RD) {
        rwperm_one(Wg, We, wc, WgP, WeLo, WeHi, wcP, gid - 3 * PER - 4096);
    }
}

// ---------------------------------------------------------------------------
// bf16x3 split MFMA GEMM, 64x128 block tile (round-8 config: measured best).
// MODE 0: plain rows -> C.
// MODE 1: FUSED launch: expert rows via slot_node (+bias, relu) || weak GEMM.
// MODE 2: rows are slots; (acc+bias)*gate -> C[slot].
// ---------------------------------------------------------------------------
template <int MODE>
__global__ __launch_bounds__(256, 5) void gemm_mfma(
    const float* __restrict__ A, int lda,
    const u16* __restrict__ BH, const u16* __restrict__ BM,
    const u16* __restrict__ BL,
    const float* __restrict__ bias,
    float* __restrict__ C, int ldc,
    const int* __restrict__ es,
    const int* __restrict__ slot_node,
    const float* __restrict__ slot_gate,
    int M, int N, int K,
    const u16* __restrict__ VH, const u16* __restrict__ VM,
    const u16* __restrict__ VL, float* __restrict__ Cw,
    int weak_base, int Mw) {
    constexpr int PL2 = 1024;   // one plane: [rowgrp2][kh2][row32][j8] u16
    __shared__ u16 sA[3 * PL2]; // 6,144 B

    int tid = threadIdx.x;
    int row0, valid_rows;
    bool isweak = false;
    if (MODE == 0) {
        row0 = blockIdx.x * 64;
        valid_rows = M - row0; if (valid_rows > 64) valid_rows = 64;
    } else if (MODE == 1 && (int)blockIdx.x >= weak_base) {
        isweak = true;
        row0 = ((int)blockIdx.x - weak_base) * 64;
        valid_rows = Mw - row0; if (valid_rows > 64) valid_rows = 64;
        if (valid_rows <= 0) return;
        BH = VH; BM = VM; BL = VL;
        C = Cw;
    } else {
        int bx = blockIdx.x, acc0 = 0, expert = -1, mt = 0;
        row0 = 0; valid_rows = 0;
        for (int e = 0; e < NEXP; e++) {
            int c = es[e + 1] - es[e];
            int t = (c + 63) >> 6;
            if (bx < acc0 + t) {
                expert = e; mt = bx - acc0; row0 = es[e] + (mt << 6);
                valid_rows = c - (mt << 6); if (valid_rows > 64) valid_rows = 64;
                break;
            }
            acc0 += t;
        }
        if (expert < 0) return;
        int bo = expert * N * K;   // max 8*256*512 = 1M elems, fits int
        BH += bo; BM += bo; BL += bo;
        bias += expert * D;
    }
    int ncol0 = blockIdx.y * 128;

    // A staging: 4 threads per row, each one float4 (4 k)
    int srow = tid >> 2;
    int koff = (tid & 3) * 4;
    int grow;
    {
        int i0 = row0 + srow;
        if (MODE == 1 && !isweak) {
            i0 = i0 < NSLOT ? i0 : NSLOT - 1;
            grow = slot_node[i0];
        } else if (MODE == 2) {
            grow = i0 < M ? i0 : M - 1;
        } else if (MODE == 1) {   // weak
            grow = i0 < Mw ? i0 : Mw - 1;
        } else {
            grow = i0 < M ? i0 : M - 1;
        }
    }
    const float* pA = A + (size_t)grow * lda + koff;
    // frag-ready write offset: [rowgrp][kh][row32][j8]
    int woff = ((srow >> 5) * 2 + (koff >> 3)) * 256 + (srow & 31) * 8 + (koff & 4);

    // fragment coords: wave owns 32 rows x 64 cols (1x2 frags)
    int lane = tid & 63;
    int wave = tid >> 6;
    int wr = (wave & 1) * 32;
    int wc = (wave >> 1) * 64;
    int fl = lane & 31;
    int K16 = K >> 4;
    int nb0 = (ncol0 + wc) >> 5;
    int tbase0 = nb0 * K16 * 512 + lane * 8;
    int tbase1 = (nb0 + 1) * K16 * 512 + lane * 8;
    int roff = ((wr >> 5) * 2 + (lane >> 5)) * 256 + fl * 8;

    f32x16 acc0 = {};
    f32x16 acc1 = {};

    for (int kt = 0; kt < K; kt += 16) {
        float4 av = *reinterpret_cast<const float4*>(pA + kt);
        int ko = (kt >> 4) * 512;
        short8v bH0 = *reinterpret_cast<const short8v*>(BH + tbase0 + ko);
        short8v bM0 = *reinterpret_cast<const short8v*>(BM + tbase0 + ko);
        short8v bL0 = *reinterpret_cast<const short8v*>(BL + tbase0 + ko);
        short8v bH1 = *reinterpret_cast<const short8v*>(BH + tbase1 + ko);
        short8v bM1 = *reinterpret_cast<const short8v*>(BM + tbase1 + ko);
        short8v bL1 = *reinterpret_cast<const short8v*>(BL + tbase1 + ko);
        __syncthreads();
        {
            u16 h0, m0, l0, h1, m1, l1, h2, m2, l2, h3, m3, l3;
            split1(av.x, h0, m0, l0);
            split1(av.y, h1, m1, l1);
            split1(av.z, h2, m2, l2);
            split1(av.w, h3, m3, l3);
            short4v hv = {(short)h0, (short)h1, (short)h2, (short)h3};
            short4v mv = {(short)m0, (short)m1, (short)m2, (short)m3};
            short4v lv = {(short)l0, (short)l1, (short)l2, (short)l3};
            *reinterpret_cast<short4v*>(&sA[0 * PL2 + woff]) = hv;
            *reinterpret_cast<short4v*>(&sA[1 * PL2 + woff]) = mv;
            *reinterpret_cast<short4v*>(&sA[2 * PL2 + woff]) = lv;
        }
        __syncthreads();
        short8v aH = *reinterpret_cast<const short8v*>(&sA[0 * PL2 + roff]);
        short8v aM = *reinterpret_cast<const short8v*>(&sA[1 * PL2 + roff]);
        short8v aL = *reinterpret_cast<const short8v*>(&sA[2 * PL2 + roff]);
#define MFMA_ACC(d, a, b) d = __builtin_amdgcn_mfma_f32_32x32x16_bf16(a, b, d, 0, 0, 0)
        MFMA_ACC(acc0, aH, bH0); MFMA_ACC(acc0, aH, bM0);
        MFMA_ACC(acc0, aM, bH0); MFMA_ACC(acc0, aH, bL0);
        MFMA_ACC(acc0, aM, bM0); MFMA_ACC(acc0, aL, bH0);
        MFMA_ACC(acc1, aH, bH1); MFMA_ACC(acc1, aH, bM1);
        MFMA_ACC(acc1, aM, bH1); MFMA_ACC(acc1, aH, bL1);
        MFMA_ACC(acc1, aM, bM1); MFMA_ACC(acc1, aL, bH1);
#undef MFMA_ACC
    }

    // epilogue: C/D layout col=lane&31, row=(reg&3)+8*(reg>>2)+4*(lane>>5)
    int fh = lane >> 5;
#pragma unroll
    for (int j = 0; j < 2; j++) {
        const f32x16& a = j ? acc1 : acc0;
        int colg = ncol0 + wc + j * 32 + fl;
        float bv = (MODE != 0 && !isweak) ? bias[colg] : 0.f;
#pragma unroll
        for (int rg = 0; rg < 16; rg++) {
            int lrow = wr + (rg & 3) + 8 * (rg >> 2) + 4 * fh;
            if (lrow >= valid_rows) continue;
            int growo = row0 + lrow;
            float v = a[rg] + bv;
            if (MODE == 1 && !isweak) {
                v = fmaxf(v, 0.f);
            } else if (MODE == 2) {
                v *= slot_gate[growo];
            }
            C[(size_t)growo * ldc + colg] = v;
        }
    }
}

// ---------------------------------------------------------------------------
extern "C" void kernel_launch(void* const* d_in, const int* in_sizes, int n_in,
                              void* d_out, int out_size, void* d_ws, size_t ws_size,
                              hipStream_t stream) {
    (void)in_sizes; (void)n_in; (void)out_size;
    const float* x    = (const float*)d_in[0];
    const int*   ei   = (const int*)d_in[1];
    const float* Wg   = (const float*)d_in[2];
    const float* We   = (const float*)d_in[3];
    const float* Ww   = (const float*)d_in[4];
    const float* W1   = (const float*)d_in[5];
    const float* b1   = (const float*)d_in[6];
    const float* W2   = (const float*)d_in[7];
    const float* b2   = (const float*)d_in[8];
    const float* wcp  = (const float*)d_in[9];
    const float* Wout = (const float*)d_in[10];
    float* out = (float*)d_out;

    char* p = (char*)d_ws;
    auto alloc = [&](size_t bytes) -> char* {
        char* q = p; p += (bytes + 255) & ~(size_t)255; return q;
    };
    int*   cnt       = (int*)alloc((size_t)NN * 4);
    int*   row_start = (int*)alloc((size_t)(NN + 1) * 4);
    int*   cur       = (int*)alloc((size_t)NN * 4);
    int*   bsum      = (int*)alloc(128 * 4);
    int*   csr_src   = (int*)alloc((size_t)NEDGE * 4);
    float* r         = (float*)alloc((size_t)NN * RD * 4);
    float* hid       = (float*)alloc((size_t)NSLOT * D * 4);
    float* expout    = (float*)alloc((size_t)NSLOT * D * 4);
    float* weak      = (float*)alloc((size_t)NN * D * 4);
    float* conf      = (float*)alloc((size_t)NN * 4);
    int*   node_top  = (int*)alloc((size_t)2 * NN * 4);
    float* node_gate = (float*)alloc((size_t)2 * NN * 4);
    int*   node_slot = (int*)alloc((size_t)2 * NN * 4);
    int*   slot_node = (int*)alloc((size_t)NSLOT * 4);
    float* slot_gate = (float*)alloc((size_t)NSLOT * 4);
    int*   part      = (int*)alloc((size_t)ASSIGN_BLOCKS * NEXP * 4);
    int*   es        = (int*)alloc(64 * 4);
    int*   ecur      = (int*)alloc(64 * 4);
    // permuted router weights (3 layers x 512 rows)
    float4* WgP  = (float4*)alloc((size_t)3 * RD * 16);
    float4* WeLo = (float4*)alloc((size_t)3 * RD * 16);
    float4* WeHi = (float4*)alloc((size_t)3 * RD * 16);
    float*  wcP  = (float*)alloc((size_t)3 * RD * 4);

    // plane sizes (elems) per layer
    const size_t SZ1 = (size_t)NEXP * D * RD;   // 1,048,576
    const size_t SZ2 = (size_t)NEXP * D * D;    //   524,288
    const size_t SZW = (size_t)RD * D;          //   131,072
    const size_t SZO = (size_t)OD * D;          //    65,536
    size_t used = (size_t)(p - (char*)d_ws);
    size_t need3 = 3 * 3 * (SZ1 + SZ2 + SZW) * 2 + 3 * SZO * 2 + 16384;
    bool all3 = used + need3 <= ws_size;
    int nl = all3 ? 3 : 1;
    u16* w1tH = (u16*)alloc((size_t)nl * SZ1 * 2);
    u16* w1tM = (u16*)alloc((size_t)nl * SZ1 * 2);
    u16* w1tL = (u16*)alloc((size_t)nl * SZ1 * 2);
    u16* w2tH = (u16*)alloc((size_t)nl * SZ2 * 2);
    u16* w2tM = (u16*)alloc((size_t)nl * SZ2 * 2);
    u16* w2tL = (u16*)alloc((size_t)nl * SZ2 * 2);
    u16* wwtH = (u16*)alloc((size_t)nl * SZW * 2);
    u16* wwtM = (u16*)alloc((size_t)nl * SZW * 2);
    u16* wwtL = (u16*)alloc((size_t)nl * SZW * 2);
    u16* wotH = (u16*)alloc(SZO * 2);
    u16* wotM = (u16*)alloc(SZO * 2);
    u16* wotL = (u16*)alloc(SZO * 2);

    const int* srcp = ei;
    const int* dstp = ei + NEDGE;
    const int EB = (NEDGE + 255) / 256;

    // graph prep (once per launch)
    copy_x_zero_cnt_k<<<5000, 256, 0, stream>>>(x, r, cnt);
    count_edges_k<<<EB, 256, 0, stream>>>(dstp, cnt);
    block_sums_k<<<NODE_BLOCKS, 256, 0, stream>>>(cnt, bsum);
    scan_bsums_k<<<1, 64, 0, stream>>>(bsum, row_start);
    block_scan_k<<<NODE_BLOCKS, 256, 0, stream>>>(cnt, bsum, row_start, cur);
    fill_csr_k<<<EB, 256, 0, stream>>>(srcp, dstp, cur, csr_src);
    if (all3) {
        // all weight planes (3 layers + Wout) + router perm in one launch
        btile_all_k<<<2519, 256, 0, stream>>>(W1, w1tH, w1tM, w1tL,
                                              W2, w2tH, w2tM, w2tL,
                                              Ww, wwtH, wwtM, wwtL,
                                              Wout, wotH, wotM, wotL,
                                              Wg, We, wcp, WgP, WeLo, WeHi, wcP);
    } else {
        btile_k<<<16, 256, 0, stream>>>(Wout, wotH, wotM, wotL, D, OD, 4096);
        rw_perm_k<<<6, 256, 0, stream>>>(Wg, We, wcp, WgP, WeLo, WeHi, wcP);
    }

    for (int l = 0; l < 3; l++) {
        if (!all3) {
            btile3_k<<<832, 256, 0, stream>>>(
                W1 + (size_t)l * NEXP * RD * D, w1tH, w1tM, w1tL,
                W2 + (size_t)l * NEXP * D * D,  w2tH, w2tM, w2tL,
                Ww + (size_t)l * RD * D,        wwtH, wwtM, wwtL);
        }
        size_t o1 = all3 ? (size_t)l * SZ1 : 0;
        size_t o2 = all3 ? (size_t)l * SZ2 : 0;
        size_t ow = all3 ? (size_t)l * SZW : 0;

        agg_router_k<<<5000, 256, 0, stream>>>(r, row_start, csr_src,
            WgP + (size_t)l * RD, WeLo + (size_t)l * RD, WeHi + (size_t)l * RD,
            wcP + (size_t)l * RD, node_top, node_gate, conf);
        hist_part_k<<<ASSIGN_BLOCKS, 256, 0, stream>>>(node_top, part);
        scan2_k<<<1, 64, 0, stream>>>(part, es, ecur);
        fill_experts_k<<<ASSIGN_BLOCKS, 256, 0, stream>>>(node_top, node_gate, es, ecur,
                                                          slot_node, slot_gate, node_slot);
        // FUSED: hid[slot] = relu(r[node]@W1[e]+b1[e])  ||  weak = r@Ww
        gemm_mfma<1><<<dim3(EXP_BLOCKS + 313, 2), 256, 0, stream>>>(
            r, RD, w1tH + o1, w1tM + o1, w1tL + o1, b1 + (size_t)l * NEXP * D, hid, D,
            es, slot_node, slot_gate, NSLOT, D, RD,
            wwtH + ow, wwtM + ow, wwtL + ow, weak, EXP_BLOCKS, NN);
        // expout[slot] = (hid[slot]@W2[e]+b2[e])*gate[slot]  (slot-indexed store)
        gemm_mfma<2><<<dim3(EXP_BLOCKS, 2), 256, 0, stream>>>(
            hid, D, w2tH + o2, w2tM + o2, w2tL + o2, b2 + (size_t)l * NEXP * D, expout, D,
            es, slot_node, slot_gate, NSLOT, D, D,
            nullptr, nullptr, nullptr, nullptr, 1 << 30, 0);
        combine_k<<<5000, 256, 0, stream>>>(expout, weak, conf, node_slot, r);
    }
    // out = h @ Wout  (h = r[:, :256], so K=256 over lda=512)
    gemm_mfma<0><<<dim3(313, 1), 256, 0, stream>>>(
        r, RD, wotH, wotM, wotL, nullptr, out, OD,
        nullptr, nullptr, nullptr, NN, OD, D,
        nullptr, nullptr, nullptr, nullptr, 1 << 30, 0);
}